// Round 3
// baseline (8162.160 us; speedup 1.0000x reference)
//
#include <hip/hip_runtime.h>
#include <hip/hip_bf16.h>

// Problem: B=256, T=512, H=512, O=2 relu-RNN. All inputs AND outputs fp32.
// d_out layout (fp32 elements): out[B,O]=512 | hidden[B,H]=131072 |
//   net_units[B,T,H]=67108864 | read_out_units[B,T,O]=262144
// d_ws: 2 x [B,H] fp32 ping-pong hidden-state buffers (1 MB).

#define B_ 256
#define T_ 512
#define H_ 512

// One timestep: h_new[b,hj] = relu(xp + sum_k h_prev[b,k]*W_hh[hj,k] + b_hh + sg*noise)
// Grid: 256 blocks = 32 batch-groups (8 rows) x 8 col-groups (64 cols). 256 threads.
// thread -> j = tid&63 (col within group), bb = tid>>6 (0..3); computes rows bb and bb+4.
__global__ __launch_bounds__(256) void step_kernel(
    const float* __restrict__ input,  // [B,T,2]
    const float* __restrict__ sigma,  // [1]
    const float* __restrict__ noise,  // [B,T,H]
    const float* __restrict__ W_in,   // [H,2]
    const float* __restrict__ b_in,   // [H]
    const float* __restrict__ W_hh,   // [H,H]
    const float* __restrict__ b_hh,   // [H]
    const float* __restrict__ hprev,  // [B,H] fp32
    float* __restrict__ hcur,         // [B,H] fp32
    float* __restrict__ net,          // [B,T,H] fp32
    int t)
{
    __shared__ float h_s[8][H_];     // 16 KB: h_prev tile (fp32)
    __shared__ float w_s[64][65];    // 16.6 KB: W chunk (fp32, padded)

    const int tid = threadIdx.x;
    const int jg  = blockIdx.x & 7;
    const int bg  = blockIdx.x >> 3;
    const int j   = tid & 63;
    const int bb  = tid >> 6;
    const int hj  = jg * 64 + j;
    const int b0  = bg * 8;

    // ---- stage h_prev[8][512] (fp32) into LDS ----
    if (t == 0) {
        for (int i = tid; i < 8 * 128; i += 256)
            ((float4*)h_s)[i] = make_float4(0.f, 0.f, 0.f, 0.f);
    } else {
        for (int i = tid; i < 8 * 128; i += 256) {
            int br = i >> 7;   // 0..7
            int c  = i & 127;  // float4 index in row
            ((float4*)&h_s[br][0])[c] =
                ((const float4*)&hprev[(size_t)(b0 + br) * H_])[c];
        }
    }

    float acc0 = 0.f, acc1 = 0.f;

    for (int kc = 0; kc < 8; ++kc) {
        __syncthreads();
        // stage W_hh[jg*64 + r][kc*64 .. +63] -> w_s[r][0..63] (fp32 float4)
        for (int i = tid; i < 1024; i += 256) {
            int r = i >> 4;    // 0..63
            int c = i & 15;    // float4 index within 64-col chunk
            float4 v = ((const float4*)(W_hh + (size_t)(jg * 64 + r) * H_ + kc * 64))[c];
            w_s[r][c * 4 + 0] = v.x;
            w_s[r][c * 4 + 1] = v.y;
            w_s[r][c * 4 + 2] = v.z;
            w_s[r][c * 4 + 3] = v.w;
        }
        __syncthreads();

        const float* hr0 = &h_s[bb][kc * 64];
        const float* hr1 = &h_s[bb + 4][kc * 64];
        const float* wr  = &w_s[j][0];
        #pragma unroll
        for (int k = 0; k < 64; ++k) {
            float w = wr[k];
            acc0 = fmaf(hr0[k], w, acc0);
            acc1 = fmaf(hr1[k], w, acc1);
        }
    }

    // ---- epilogue: xp + biases + noise, relu, store ----
    const float xw0 = W_in[2 * hj];
    const float xw1 = W_in[2 * hj + 1];
    const float bib = b_in[hj] + b_hh[hj];
    const float sg  = sigma[0];

    float accs[2] = {acc0, acc1};
    #pragma unroll
    for (int q = 0; q < 2; ++q) {
        int b = b0 + bb + 4 * q;
        float in0 = input[((size_t)b * T_ + t) * 2 + 0];
        float in1 = input[((size_t)b * T_ + t) * 2 + 1];
        float nz  = noise[((size_t)b * T_ + t) * H_ + hj];
        float v = accs[q] + in0 * xw0 + in1 * xw1 + bib + sg * nz;
        v = v > 0.f ? v : 0.f;
        hcur[(size_t)b * H_ + hj] = v;
        net[((size_t)b * T_ + t) * H_ + hj] = v;
    }
}

// out[b,:] = h_last[b,:] @ W_fc^T + b_fc ; hidden[b,:] = h_last[b,:]
__global__ __launch_bounds__(256) void final_kernel(
    const float* __restrict__ hlast, // [B,H] fp32
    const float* __restrict__ W_fc,  // [O,H]
    const float* __restrict__ b_fc,  // [O]
    float* __restrict__ out,         // [B,O]
    float* __restrict__ hidden)      // [B,H]
{
    __shared__ float red[2][256];
    int b = blockIdx.x;
    int tid = threadIdx.x;
    float a0 = 0.f, a1 = 0.f;
    for (int h = tid; h < H_; h += 256) {
        float v = hlast[(size_t)b * H_ + h];
        hidden[(size_t)b * H_ + h] = v;
        a0 = fmaf(v, W_fc[h], a0);
        a1 = fmaf(v, W_fc[H_ + h], a1);
    }
    red[0][tid] = a0; red[1][tid] = a1;
    __syncthreads();
    for (int s = 128; s > 0; s >>= 1) {
        if (tid < s) {
            red[0][tid] += red[0][tid + s];
            red[1][tid] += red[1][tid + s];
        }
        __syncthreads();
    }
    if (tid == 0) {
        out[b * 2 + 0] = red[0][0] + b_fc[0];
        out[b * 2 + 1] = red[1][0] + b_fc[1];
    }
}

// read_out_units[b,t,:] = net[b,t,:] @ W_fc^T + b_fc. One wave per (b,t).
// lane handles h = lane*8 .. lane*8+7 (two float4 loads of net and of each W_fc row).
__global__ __launch_bounds__(256) void readout_kernel(
    const float* __restrict__ net,  // [B*T, H] fp32
    const float* __restrict__ W_fc, // [O,H] fp32
    const float* __restrict__ b_fc, // [O]
    float* __restrict__ ro)         // [B*T, O]
{
    int wave = threadIdx.x >> 6;
    int lane = threadIdx.x & 63;
    int idx  = blockIdx.x * 4 + wave;   // flattened (b,t)

    const float4* nrow = (const float4*)(net + (size_t)idx * H_);
    float4 n0 = nrow[lane * 2];
    float4 n1 = nrow[lane * 2 + 1];
    float4 w0a = ((const float4*)W_fc)[lane * 2];
    float4 w0b = ((const float4*)W_fc)[lane * 2 + 1];
    float4 w1a = ((const float4*)(W_fc + H_))[lane * 2];
    float4 w1b = ((const float4*)(W_fc + H_))[lane * 2 + 1];

    float a0, a1;
    a0  = n0.x * w0a.x + n0.y * w0a.y + n0.z * w0a.z + n0.w * w0a.w;
    a0 += n1.x * w0b.x + n1.y * w0b.y + n1.z * w0b.z + n1.w * w0b.w;
    a1  = n0.x * w1a.x + n0.y * w1a.y + n0.z * w1a.z + n0.w * w1a.w;
    a1 += n1.x * w1b.x + n1.y * w1b.y + n1.z * w1b.z + n1.w * w1b.w;

    #pragma unroll
    for (int off = 32; off > 0; off >>= 1) {
        a0 += __shfl_down(a0, off);
        a1 += __shfl_down(a1, off);
    }
    if (lane == 0) {
        ro[(size_t)idx * 2 + 0] = a0 + b_fc[0];
        ro[(size_t)idx * 2 + 1] = a1 + b_fc[1];
    }
}

extern "C" void kernel_launch(void* const* d_in, const int* in_sizes, int n_in,
                              void* d_out, int out_size, void* d_ws, size_t ws_size,
                              hipStream_t stream)
{
    const float* input = (const float*)d_in[0];
    const float* sigma = (const float*)d_in[1];
    const float* noise = (const float*)d_in[2];
    const float* W_in  = (const float*)d_in[3];
    const float* b_in  = (const float*)d_in[4];
    const float* W_hh  = (const float*)d_in[5];
    const float* b_hh  = (const float*)d_in[6];
    const float* W_fc  = (const float*)d_in[7];
    const float* b_fc  = (const float*)d_in[8];

    float* out    = (float*)d_out;                   // [B,O]
    float* hidden = out + (size_t)B_ * 2;            // [B,H]
    float* net    = hidden + (size_t)B_ * H_;        // [B,T,H]
    float* ro     = net + (size_t)B_ * T_ * H_;      // [B,T,O]

    float* ws0 = (float*)d_ws;                       // [B,H] fp32
    float* ws1 = ws0 + (size_t)B_ * H_;              // [B,H] fp32

    for (int t = 0; t < T_; ++t) {
        float* hcur        = (t & 1) ? ws1 : ws0;
        const float* hprev = (t & 1) ? ws0 : ws1;
        step_kernel<<<256, 256, 0, stream>>>(input, sigma, noise, W_in, b_in,
                                             W_hh, b_hh, hprev, hcur, net, t);
    }
    // T-1 = 511 is odd -> h_last in ws1
    final_kernel<<<B_, 256, 0, stream>>>(ws1, W_fc, b_fc, out, hidden);
    readout_kernel<<<(B_ * T_) / 4, 256, 0, stream>>>(net, W_fc, b_fc, ro);
}